// Round 14
// baseline (164.915 us; speedup 1.0000x reference)
//
#include <hip/hip_runtime.h>
#include <math.h>

// OnlineTripletLoss on MI355X — Round 14.
// R13: ws 17MB->80KB did NOT move the ~55us gap (total 146.4, fused 91.4). Gap is not
//      poison/prep. R1 (plain kernels) had gap ~3us -> suspect the aux-launch +
//      atomic-chain structure under graph replay.
// Changes — ONE kernel launch, zero global atomics, zero init:
//  (1) sq computed in-kernel during staging (deterministic identical order across
//      blocks -> cross-block d^2 comparisons exact).
//  (2) flag cascade: unconditional relaxed agent-scope partial stores (every slot
//      written => no init), release-stored MAGIC flags (0xAA poison != MAGIC).
//      part(py,px) -> per-py gather -> phase2 part -> px==0 reducers -> block 0 final.
//      512 blocks co-resident (57KB LDS, 512thr = 2/CU exactly).
// ws (floats): partHP[16][32][256] | partHNF | partHNS | finHP[4096] | finHNF | finHNS
//              | flag1[512*16] | flag2[512*16] | flag3[16*16]

constexpr float MARGIN = 0.3f;
constexpr unsigned MAGIC = 0x13579BDFu;

typedef _Float16 half8    __attribute__((ext_vector_type(8)));
typedef float    floatx16 __attribute__((ext_vector_type(16)));

__device__ __forceinline__ void st_agent(unsigned int* p, float v) {
    __hip_atomic_store(p, __float_as_uint(v), __ATOMIC_RELAXED, __HIP_MEMORY_SCOPE_AGENT);
}
__device__ __forceinline__ float ld_agent(const unsigned int* p) {
    return __uint_as_float(__hip_atomic_load(p, __ATOMIC_RELAXED, __HIP_MEMORY_SCOPE_AGENT));
}

__global__ __launch_bounds__(512, 4)
void fused_kernel(const float* __restrict__ e, const int* __restrict__ labels,
                  unsigned int* __restrict__ ws, float* __restrict__ out, int N, int D) {
    // per buffer (12288 halves = 24 KB): A[kcl(4)][r(256)][8] | B[kcl(4)][r(128)][8]
    __shared__ __attribute__((aligned(16))) _Float16 S[2][12288];   // 48 KB
    __shared__ float redP[256][2], redN[256][2];
    __shared__ float sq_r[256], sq_c[128], hp_r[256];
    __shared__ int   lab_r[256], lab_c[128];

    // ws layout
    unsigned int* partHP  = ws;                    // 16*32*256
    unsigned int* partHNF = partHP  + 131072;
    unsigned int* partHNS = partHNF + 131072;
    unsigned int* finHP   = partHNS + 131072;      // 4096 each
    unsigned int* finHNF  = finHP   + 4096;
    unsigned int* finHNS  = finHNF  + 4096;
    unsigned int* flag1   = finHNS  + 4096;        // 512 * 16 spacing
    unsigned int* flag2   = flag1   + 8192;
    unsigned int* flag3   = flag2   + 8192;        // 16 * 16

    const int tid  = threadIdx.x;
    const int lane = tid & 63;
    const int wave = tid >> 6;            // 0..7
    const int wr = (wave >> 1) * 64;      // 0,64,128,192
    const int wc = (wave & 1) * 64;       // 0,64
    const int mrow = lane & 31;
    const int half_id = lane >> 5;

    // XCD swizzle over the 32(px) x 16(py) tile grid
    const int j  = blockIdx.x & 7;
    const int i  = blockIdx.x >> 3;       // 0..63
    const int px = (j & 3) * 8 + (i & 7);         // 0..31 (128-col tiles)
    const int py = (j >> 2) * 8 + (i >> 3);       // 0..15 (256-row tiles)
    const int rowBase = py * 256;
    const int colBase = px * 128;
    const int slot = py * 32 + px;

    if (tid < 256) lab_r[tid] = labels[rowBase + tid];
    else if (tid < 384) lab_c[tid - 256] = labels[colBase + (tid - 256)];

    floatx16 acc[2][2];
    #pragma unroll
    for (int a = 0; a < 2; ++a)
        #pragma unroll
        for (int b = 0; b < 2; ++b)
            #pragma unroll
            for (int r = 0; r < 16; ++r) acc[a][b][r] = 0.f;

    // staging: thread -> A row srow=tid>>1, chunk sch=tid&1; threads<256 also B row.
    const int srow = tid >> 1, sch = tid & 1;
    float4 ra0, ra1, rb0, rb1;
    float sqA = 0.f, sqB = 0.f;
    auto loadRegs = [&](int kkv) {
        const float* ga = &e[(size_t)(rowBase + srow) * D + kkv * 16 + sch * 8];
        ra0 = *(const float4*)ga;
        ra1 = *(const float4*)(ga + 4);
        if (tid < 256) {
            const float* gb = &e[(size_t)(colBase + srow) * D + kkv * 16 + sch * 8];
            rb0 = *(const float4*)gb;
            rb1 = *(const float4*)(gb + 4);
        }
    };
    auto cvtWrite = [&](int b) {
        {
            const float xv[8] = {ra0.x, ra0.y, ra0.z, ra0.w, ra1.x, ra1.y, ra1.z, ra1.w};
            half8 hi, lo;
            #pragma unroll
            for (int q = 0; q < 8; ++q) {
                _Float16 h = (_Float16)xv[q];
                hi[q] = h;
                lo[q] = (_Float16)(xv[q] - (float)h);
                sqA += xv[q] * xv[q];
            }
            *(half8*)&S[b][(sch * 256 + srow) * 8]       = hi;
            *(half8*)&S[b][((2 + sch) * 256 + srow) * 8] = lo;
        }
        if (tid < 256) {
            const float xv[8] = {rb0.x, rb0.y, rb0.z, rb0.w, rb1.x, rb1.y, rb1.z, rb1.w};
            half8 hi, lo;
            #pragma unroll
            for (int q = 0; q < 8; ++q) {
                _Float16 h = (_Float16)xv[q];
                hi[q] = h;
                lo[q] = (_Float16)(xv[q] - (float)h);
                sqB += xv[q] * xv[q];
            }
            *(half8*)&S[b][8192 + (sch * 128 + srow) * 8]       = hi;
            *(half8*)&S[b][8192 + ((2 + sch) * 128 + srow) * 8] = lo;
        }
    };

    loadRegs(0);

    #pragma unroll 1
    for (int kk = 0; kk < 32; ++kk) {
        const int b = kk & 1;
        cvtWrite(b);
        __syncthreads();
        if (kk + 1 < 32) loadRegs(kk + 1);
        const int rA = wr + mrow, cB = wc + mrow;
        const half8 ah0 = *(const half8*)&S[b][(half_id * 256 + rA) * 8];
        const half8 ah1 = *(const half8*)&S[b][(half_id * 256 + rA + 32) * 8];
        const half8 al0 = *(const half8*)&S[b][((2 + half_id) * 256 + rA) * 8];
        const half8 al1 = *(const half8*)&S[b][((2 + half_id) * 256 + rA + 32) * 8];
        const half8 bh0 = *(const half8*)&S[b][8192 + (half_id * 128 + cB) * 8];
        const half8 bh1 = *(const half8*)&S[b][8192 + (half_id * 128 + cB + 32) * 8];
        const half8 bl0 = *(const half8*)&S[b][8192 + ((2 + half_id) * 128 + cB) * 8];
        const half8 bl1 = *(const half8*)&S[b][8192 + ((2 + half_id) * 128 + cB + 32) * 8];
        acc[0][0] = __builtin_amdgcn_mfma_f32_32x32x16_f16(bh0, ah0, acc[0][0], 0, 0, 0);
        acc[0][1] = __builtin_amdgcn_mfma_f32_32x32x16_f16(bh0, ah1, acc[0][1], 0, 0, 0);
        acc[1][0] = __builtin_amdgcn_mfma_f32_32x32x16_f16(bh1, ah0, acc[1][0], 0, 0, 0);
        acc[1][1] = __builtin_amdgcn_mfma_f32_32x32x16_f16(bh1, ah1, acc[1][1], 0, 0, 0);
        acc[0][0] = __builtin_amdgcn_mfma_f32_32x32x16_f16(bl0, ah0, acc[0][0], 0, 0, 0);
        acc[0][1] = __builtin_amdgcn_mfma_f32_32x32x16_f16(bl0, ah1, acc[0][1], 0, 0, 0);
        acc[1][0] = __builtin_amdgcn_mfma_f32_32x32x16_f16(bl1, ah0, acc[1][0], 0, 0, 0);
        acc[1][1] = __builtin_amdgcn_mfma_f32_32x32x16_f16(bl1, ah1, acc[1][1], 0, 0, 0);
        acc[0][0] = __builtin_amdgcn_mfma_f32_32x32x16_f16(bh0, al0, acc[0][0], 0, 0, 0);
        acc[0][1] = __builtin_amdgcn_mfma_f32_32x32x16_f16(bh0, al1, acc[0][1], 0, 0, 0);
        acc[1][0] = __builtin_amdgcn_mfma_f32_32x32x16_f16(bh1, al0, acc[1][0], 0, 0, 0);
        acc[1][1] = __builtin_amdgcn_mfma_f32_32x32x16_f16(bh1, al1, acc[1][1], 0, 0, 0);
    }

    // sq combine (pair lanes share a row; identical order in every block)
    {
        float a = sqA + __shfl_xor(sqA, 1, 64);
        if ((tid & 1) == 0) sq_r[srow] = a;
        if (tid < 256) {
            float b2 = sqB + __shfl_xor(sqB, 1, 64);
            if ((tid & 1) == 0) sq_c[srow] = b2;
        }
    }
    __syncthreads();

    float sqr[2]; int labr[2];
    #pragma unroll
    for (int ai = 0; ai < 2; ++ai) {
        sqr[ai]  = sq_r[wr + ai * 32 + mrow];
        labr[ai] = lab_r[wr + ai * 32 + mrow];
    }

    // ---- phase 1: per-block row maxima of d^2 (pos / neg) ----
    #pragma unroll
    for (int ai = 0; ai < 2; ++ai) {
        float vp = 0.f, vn = 0.f;
        #pragma unroll
        for (int bj = 0; bj < 2; ++bj)
            #pragma unroll
            for (int r = 0; r < 16; ++r) {
                const int c = wc + bj * 32 + (r & 3) + 8 * (r >> 2) + 4 * half_id;
                const float d2 = fmaxf(sqr[ai] + sq_c[c] - 2.0f * acc[bj][ai][r], 1e-12f);
                const bool pos = (labr[ai] == lab_c[c]);
                vp = fmaxf(vp, pos ? d2 : 0.f);
                vn = fmaxf(vn, pos ? 0.f : d2);
            }
        vp = fmaxf(vp, __shfl_xor(vp, 32, 64));
        vn = fmaxf(vn, __shfl_xor(vn, 32, 64));
        if (half_id == 0) {
            redP[wr + ai * 32 + mrow][wave & 1] = vp;
            redN[wr + ai * 32 + mrow][wave & 1] = vn;
        }
    }
    __syncthreads();
    if (tid < 256) {
        st_agent(&partHP[slot * 256 + tid],  fmaxf(redP[tid][0], redP[tid][1]));
        st_agent(&partHNF[slot * 256 + tid], fmaxf(redN[tid][0], redN[tid][1]));
    }
    __syncthreads();                              // drains all stores (vmcnt 0)
    if (tid == 0) {
        __threadfence();
        __hip_atomic_store(&flag1[slot * 16], MAGIC, __ATOMIC_RELEASE, __HIP_MEMORY_SCOPE_AGENT);
    }

    // ---- wait for all 32 col-blocks of my row-panel, gather hp ----
    if (tid < 32) {
        while (__hip_atomic_load(&flag1[(py * 32 + tid) * 16], __ATOMIC_ACQUIRE,
                                 __HIP_MEMORY_SCOPE_AGENT) != MAGIC)
            __builtin_amdgcn_s_sleep(16);
    }
    __syncthreads();
    if (tid < 256) {
        float m = 0.f;
        #pragma unroll 4
        for (int q = 0; q < 32; ++q)
            m = fmaxf(m, ld_agent(&partHP[(py * 32 + q) * 256 + tid]));
        hp_r[tid] = m;
    }
    __syncthreads();

    // ---- phase 2: hn_semi partial = min{d2 : neg, d2 > hp2} ----
    #pragma unroll
    for (int ai = 0; ai < 2; ++ai) {
        const float hpv2 = hp_r[wr + ai * 32 + mrow];
        float vm = __builtin_inff();
        #pragma unroll
        for (int bj = 0; bj < 2; ++bj)
            #pragma unroll
            for (int r = 0; r < 16; ++r) {
                const int c = wc + bj * 32 + (r & 3) + 8 * (r >> 2) + 4 * half_id;
                const float d2 = fmaxf(sqr[ai] + sq_c[c] - 2.0f * acc[bj][ai][r], 1e-12f);
                const bool cand = (labr[ai] != lab_c[c]) && (d2 > hpv2);
                vm = fminf(vm, cand ? d2 : __builtin_inff());
            }
        vm = fminf(vm, __shfl_xor(vm, 32, 64));
        if (half_id == 0) redP[wr + ai * 32 + mrow][wave & 1] = vm;
    }
    __syncthreads();
    if (tid < 256)
        st_agent(&partHNS[slot * 256 + tid], fminf(redP[tid][0], redP[tid][1]));
    __syncthreads();
    if (tid == 0) {
        __threadfence();
        __hip_atomic_store(&flag2[slot * 16], MAGIC, __ATOMIC_RELEASE, __HIP_MEMORY_SCOPE_AGENT);
    }

    // ---- px==0 blocks: reduce partials -> finals for their row-panel ----
    if (px == 0) {
        if (tid < 32) {
            while (__hip_atomic_load(&flag2[(py * 32 + tid) * 16], __ATOMIC_ACQUIRE,
                                     __HIP_MEMORY_SCOPE_AGENT) != MAGIC)
                __builtin_amdgcn_s_sleep(16);
        }
        __syncthreads();
        if (tid < 256) {
            float mf = 0.f, ms = __builtin_inff();
            #pragma unroll 4
            for (int q = 0; q < 32; ++q) {
                mf = fmaxf(mf, ld_agent(&partHNF[(py * 32 + q) * 256 + tid]));
                ms = fminf(ms, ld_agent(&partHNS[(py * 32 + q) * 256 + tid]));
            }
            st_agent(&finHP[rowBase + tid],  hp_r[tid]);
            st_agent(&finHNF[rowBase + tid], mf);
            st_agent(&finHNS[rowBase + tid], ms);
        }
        __syncthreads();
        if (tid == 0) {
            __threadfence();
            __hip_atomic_store(&flag3[py * 16], MAGIC, __ATOMIC_RELEASE, __HIP_MEMORY_SCOPE_AGENT);
        }
    }

    // ---- block 0: final loss ----
    if (blockIdx.x != 0) return;
    if (tid < 16) {
        while (__hip_atomic_load(&flag3[tid * 16], __ATOMIC_ACQUIRE,
                                 __HIP_MEMORY_SCOPE_AGENT) != MAGIC)
            __builtin_amdgcn_s_sleep(16);
    }
    __syncthreads();

    float* FS = (float*)&S[0][0];
    int*   IC = (int*)(FS + 512);
    int*   IA = IC + 512;
    int any = 0;
    for (int r = tid; r < N; r += 512) {
        float h  = sqrtf(ld_agent(&finHP[r]));
        float hs = sqrtf(ld_agent(&finHNS[r]));
        any |= (hs < h + MARGIN) ? 1 : 0;
    }
    IA[tid] = any;
    __syncthreads();
    for (int s = 256; s; s >>= 1) {
        if (tid < s) IA[tid] |= IA[tid + s];
        __syncthreads();
    }
    const bool has_semi = IA[0] != 0;
    float sum = 0.f; int valid = 0;
    for (int r = tid; r < N; r += 512) {
        float h  = sqrtf(ld_agent(&finHP[r]));
        float hn = has_semi ? sqrtf(ld_agent(&finHNS[r])) : sqrtf(ld_agent(&finHNF[r]));
        float t = fmaxf(h - hn + MARGIN, 0.f);
        if (!(t > 0.f)) t = 0.f;        // -inf guard (hn=+inf rows)
        sum += t;
        valid += (t > 0.f) ? 1 : 0;
    }
    FS[tid] = sum; IC[tid] = valid;
    __syncthreads();
    for (int s = 256; s; s >>= 1) {
        if (tid < s) { FS[tid] += FS[tid + s]; IC[tid] += IC[tid + s]; }
        __syncthreads();
    }
    if (tid == 0) {
        float total = FS[0]; int v = IC[0];
        out[0] = (v > 0) ? (total / (float)v) : (total / (float)N);
    }
}

extern "C" void kernel_launch(void* const* d_in, const int* in_sizes, int n_in,
                              void* d_out, int out_size, void* d_ws, size_t ws_size,
                              hipStream_t stream) {
    const float* e      = (const float*)d_in[0];
    const int*   labels = (const int*)d_in[1];
    const int N = in_sizes[1];
    const int D = in_sizes[0] / N;
    float* out = (float*)d_out;

    const int ntx = N / 128, nty = N / 256;  // 32 x 16 tiles = 512 blocks = 2/CU
    fused_kernel<<<ntx * nty, 512, 0, stream>>>(e, labels, (unsigned int*)d_ws, out, N, D);
}

// Round 15
// 150.985 us; speedup vs baseline: 1.0923x; 1.0923x over previous
//
#include <hip/hip_runtime.h>
#include <math.h>

// OnlineTripletLoss on MI355X — Round 15.
// R14: single-kernel did NOT remove the ~52us gap (164.9 = 113 fused + 52) -> gap is
//      fixed harness/replay overhead, invariant across all structures since R2.
//      Strategy: minimize profiled kernel sum. R10 champion (prep ~4 + fused 82.8).
// Change (vs R10): A-operands read DIRECTLY from pan global (R9-verified addressing;
//      pan IS the frag layout), only B staged via DMA->LDS. Per-CU-per-kk DS pipe
//      1920 -> ~960 cyc (< MFMA 1536): LDS no longer co-bottleneck. A loads issued
//      BEFORE the B-DMA each kk so MFMA's vmcnt wait covers only A (~200cyc L2), not
//      the next tile's DMA. LDS 53.8 -> ~20 KB. Everything else frozen from R10.
// ws: sq[N] | hp2[N] | hnf2[N] | hns2[N] | bars[1024] | pad | pan[N*2D] f16

constexpr float MARGIN = 0.3f;

typedef _Float16 half8    __attribute__((ext_vector_type(8)));
typedef float    floatx16 __attribute__((ext_vector_type(16)));

#define GLD_LDS16(gp, lp)                                                              \
    __builtin_amdgcn_global_load_lds(                                                  \
        (const __attribute__((address_space(1))) void*)(gp),                           \
        (__attribute__((address_space(3))) void*)(lp), 16, 0, 0)

// prep (R10 v1): 32 rows/block; builds pan[p][kc][r][8] (kc<64 hi, kc>=64 lo),
// sq, per-row init, barrier counters.
__global__ __launch_bounds__(256)
void prep_kernel(const float* __restrict__ e, _Float16* __restrict__ pan,
                 float* __restrict__ sq, unsigned int* __restrict__ hp,
                 unsigned int* __restrict__ hn_fall, unsigned int* __restrict__ hn_semi,
                 unsigned int* __restrict__ bars, int N, int D) {
    if (blockIdx.x == 0 && threadIdx.x < 32) bars[threadIdx.x * 32] = 0u;
    const int r0  = blockIdx.x * 32;
    const int p   = r0 >> 7;
    const int rl  = r0 & 127;
    const int r   = threadIdx.x >> 3;
    const int c8  = threadIdx.x & 7;
    const int row = r0 + r;
    const float* er = e + (size_t)row * D;
    float s = 0.f;
    #pragma unroll
    for (int it = 0; it < 8; ++it) {
        const int kw = c8 + it * 8;
        const float4 x0 = *(const float4*)&er[kw * 8];
        const float4 x1 = *(const float4*)&er[kw * 8 + 4];
        const float xv[8] = {x0.x, x0.y, x0.z, x0.w, x1.x, x1.y, x1.z, x1.w};
        half8 hi, lo;
        #pragma unroll
        for (int j = 0; j < 8; ++j) {
            _Float16 h = (_Float16)xv[j];
            hi[j] = h;
            lo[j] = (_Float16)(xv[j] - (float)h);
            s += xv[j] * xv[j];
        }
        *(half8*)&pan[((size_t)(p * 128 + kw) * 128 + rl + r) * 8]      = hi;
        *(half8*)&pan[((size_t)(p * 128 + 64 + kw) * 128 + rl + r) * 8] = lo;
    }
    s += __shfl_down(s, 4, 8);
    s += __shfl_down(s, 2, 8);
    s += __shfl_down(s, 1, 8);
    if (c8 == 0) {
        sq[row]      = s;
        hp[row]      = 0u;           // max identity (dist >= 0)
        hn_fall[row] = 0u;
        hn_semi[row] = 0x7f800000u;  // +inf (min identity)
    }
}

// Fused kernel: tile 256(rows) x 128(cols), 512 thr = 8 waves (4x2) of 64x64.
// A frags direct from global pan; B double-buffered via DMA->LDS. Swapped-operand
// MFMA, per-row-panel barrier, last-block final reduction.
__global__ __launch_bounds__(512, 4)
void fused_kernel(const _Float16* __restrict__ pan, const int* __restrict__ labels,
                  const float* __restrict__ sq,
                  unsigned int* __restrict__ hp,
                  unsigned int* __restrict__ hn_fall,
                  unsigned int* __restrict__ hn_semi,
                  unsigned int* __restrict__ bars,
                  float* __restrict__ out,
                  int N, int D, unsigned int nrowblocks, unsigned int nblocks) {
    // per buffer (4096 halves = 8 KB): B[kcl(4)][r(128)][8]; kcl 0,1 hi / 2,3 lo
    __shared__ __attribute__((aligned(16))) _Float16 S[2][4096];   // 16 KB
    __shared__ float sq_r[256], sq_c[128], hp_r[256];
    __shared__ int   lab_r[256], lab_c[128];
    __shared__ int   lastflag;

    const int tid  = threadIdx.x;
    const int lane = tid & 63;
    const int wave = tid >> 6;            // 0..7
    const int wr = (wave >> 1) * 64;      // 0,64,128,192
    const int wc = (wave & 1) * 64;       // 0,64
    const int mrow = lane & 31;
    const int half_id = lane >> 5;

    const int j  = blockIdx.x & 7;
    const int i  = blockIdx.x >> 3;       // 0..63
    const int px = (j & 3) * 8 + (i & 7);         // 0..31 (128-col tiles)
    const int py = (j >> 2) * 8 + (i >> 3);       // 0..15 (256-row tiles)
    const int rowBase = py * 256;
    const int colBase = px * 128;

    if (tid < 256) {
        sq_r[tid]  = sq[rowBase + tid];
        lab_r[tid] = labels[rowBase + tid];
    } else if (tid < 384) {
        const int t = tid - 256;
        sq_c[t]  = sq[colBase + t];
        lab_c[t] = labels[colBase + t];
    }

    floatx16 acc[2][2];
    #pragma unroll
    for (int a = 0; a < 2; ++a)
        #pragma unroll
        for (int b = 0; b < 2; ++b)
            #pragma unroll
            for (int r = 0; r < 16; ++r) acc[a][b][r] = 0.f;

    // A frag base (direct global): panel pA = 2*py + (wr>>7), row = (wr&127)+mrow,
    // kc starts at half_id; per k16-step kc += 2 -> +2048 halves. lo at +64 planes.
    const int pA = 2 * py + (wr >> 7);
    const size_t aBase = ((size_t)(pA * 128 + half_id) * 128 + (wr & 127) + mrow) * 8;
    const size_t loOff = (size_t)64 * 128 * 8;

    // B staging: 8 slabs of 1KB per stage, wave w issues slab w.
    auto stageB = [&](int b, int kkv) {
        const int kcl = wave >> 1, rh = wave & 1;
        const int kc = (kcl < 2) ? (2 * kkv + kcl) : (64 + 2 * kkv + (kcl - 2));
        const _Float16* g = pan + ((size_t)(px * 128 + kc) * 128 + rh * 64 + lane) * 8;
        GLD_LDS16(g, &S[b][(kcl * 128 + rh * 64) * 8]);
    };

    stageB(0, 0);

    #pragma unroll 1
    for (int kk = 0; kk < 32; ++kk) {
        const int b = kk & 1;
        // A loads FIRST (oldest in vmcnt queue), then next B-DMA, then barrier-free use
        const _Float16* ga = pan + aBase + (size_t)kk * 2048;
        const half8 ah0 = *(const half8*)(ga);
        const half8 ah1 = *(const half8*)(ga + 256);
        const half8 al0 = *(const half8*)(ga + loOff);
        const half8 al1 = *(const half8*)(ga + loOff + 256);
        __syncthreads();               // B(kk) visible (drains DMA issued last iter)
        if (kk + 1 < 32) stageB(b ^ 1, kk + 1);
        const int cB = wc + mrow;
        const half8 bh0 = *(const half8*)&S[b][(half_id * 128 + cB) * 8];
        const half8 bh1 = *(const half8*)&S[b][(half_id * 128 + cB + 32) * 8];
        const half8 bl0 = *(const half8*)&S[b][((2 + half_id) * 128 + cB) * 8];
        const half8 bl1 = *(const half8*)&S[b][((2 + half_id) * 128 + cB + 32) * 8];
        // swapped operands: D[col(reg)][row(lane)] ; dot = hi.hi + lo.hi + hi.lo
        acc[0][0] = __builtin_amdgcn_mfma_f32_32x32x16_f16(bh0, ah0, acc[0][0], 0, 0, 0);
        acc[0][1] = __builtin_amdgcn_mfma_f32_32x32x16_f16(bh0, ah1, acc[0][1], 0, 0, 0);
        acc[1][0] = __builtin_amdgcn_mfma_f32_32x32x16_f16(bh1, ah0, acc[1][0], 0, 0, 0);
        acc[1][1] = __builtin_amdgcn_mfma_f32_32x32x16_f16(bh1, ah1, acc[1][1], 0, 0, 0);
        acc[0][0] = __builtin_amdgcn_mfma_f32_32x32x16_f16(bl0, ah0, acc[0][0], 0, 0, 0);
        acc[0][1] = __builtin_amdgcn_mfma_f32_32x32x16_f16(bl0, ah1, acc[0][1], 0, 0, 0);
        acc[1][0] = __builtin_amdgcn_mfma_f32_32x32x16_f16(bl1, ah0, acc[1][0], 0, 0, 0);
        acc[1][1] = __builtin_amdgcn_mfma_f32_32x32x16_f16(bl1, ah1, acc[1][1], 0, 0, 0);
        acc[0][0] = __builtin_amdgcn_mfma_f32_32x32x16_f16(bh0, al0, acc[0][0], 0, 0, 0);
        acc[0][1] = __builtin_amdgcn_mfma_f32_32x32x16_f16(bh0, al1, acc[0][1], 0, 0, 0);
        acc[1][0] = __builtin_amdgcn_mfma_f32_32x32x16_f16(bh1, al0, acc[1][0], 0, 0, 0);
        acc[1][1] = __builtin_amdgcn_mfma_f32_32x32x16_f16(bh1, al1, acc[1][1], 0, 0, 0);
    }

    // ---- epilogue: rows in lanes. row(ai) = wr + ai*32 + mrow ----
    float sqr[2]; int labr[2];
    #pragma unroll
    for (int ai = 0; ai < 2; ++ai) {
        sqr[ai]  = sq_r[wr + ai * 32 + mrow];
        labr[ai] = lab_r[wr + ai * 32 + mrow];
    }

    // ---- phase 1: hp / hn_fall ----
    #pragma unroll
    for (int ai = 0; ai < 2; ++ai) {
        float vp = 0.f, vn = 0.f;
        #pragma unroll
        for (int bj = 0; bj < 2; ++bj) {
            #pragma unroll
            for (int r = 0; r < 16; ++r) {
                const int c = wc + bj * 32 + (r & 3) + 8 * (r >> 2) + 4 * half_id;
                float d = sqrtf(fmaxf(sqr[ai] + sq_c[c] - 2.0f * acc[bj][ai][r], 1e-12f));
                const bool pos = (labr[ai] == lab_c[c]);
                vp = fmaxf(vp, pos ? d : 0.f);
                vn = fmaxf(vn, pos ? 0.f : d);
            }
        }
        vp = fmaxf(vp, __shfl_xor(vp, 32, 64));
        vn = fmaxf(vn, __shfl_xor(vn, 32, 64));
        if (half_id == 0) {
            atomicMax(&hp[rowBase + wr + ai * 32 + mrow],      __float_as_uint(vp));
            atomicMax(&hn_fall[rowBase + wr + ai * 32 + mrow], __float_as_uint(vn));
        }
    }

    // ---- per-row-panel barrier: the 32 blocks sharing py ----
    __syncthreads();
    unsigned int* ctr = &bars[py * 32];
    if (tid == 0) {
        __threadfence();
        atomicAdd(ctr, 1u);
        while (__hip_atomic_load(ctr, __ATOMIC_ACQUIRE, __HIP_MEMORY_SCOPE_AGENT)
               < nrowblocks)
            __builtin_amdgcn_s_sleep(32);
    }
    __syncthreads();
    if (tid < 256)
        hp_r[tid] = __uint_as_float(__hip_atomic_load(&hp[rowBase + tid],
                                    __ATOMIC_RELAXED, __HIP_MEMORY_SCOPE_AGENT));
    __syncthreads();

    // ---- phase 2: hn_semi = min{d : neg, d > hp} ----
    #pragma unroll
    for (int ai = 0; ai < 2; ++ai) {
        const float hpv = hp_r[wr + ai * 32 + mrow];
        float vm = __builtin_inff();
        #pragma unroll
        for (int bj = 0; bj < 2; ++bj) {
            #pragma unroll
            for (int r = 0; r < 16; ++r) {
                const int c = wc + bj * 32 + (r & 3) + 8 * (r >> 2) + 4 * half_id;
                float d = sqrtf(fmaxf(sqr[ai] + sq_c[c] - 2.0f * acc[bj][ai][r], 1e-12f));
                const bool cand = (labr[ai] != lab_c[c]) && (d > hpv);
                vm = fminf(vm, cand ? d : __builtin_inff());
            }
        }
        vm = fminf(vm, __shfl_xor(vm, 32, 64));
        if (half_id == 0)
            atomicMin(&hn_semi[rowBase + wr + ai * 32 + mrow], __float_as_uint(vm));
    }

    // ---- last-block final reduction ----
    __syncthreads();
    if (tid == 0) {
        __threadfence();
        unsigned int old = atomicAdd(&bars[992], 1u);
        lastflag = (old == nblocks - 1) ? 1 : 0;
    }
    __syncthreads();
    if (!lastflag) return;
    if (tid == 0) __threadfence();
    __syncthreads();

    float* FS = (float*)&S[0][0];
    int*   IC = (int*)(FS + 512);
    int*   IA = IC + 512;
    int any = 0;
    for (int r = tid; r < N; r += 512) {
        float h  = __uint_as_float(__hip_atomic_load(&hp[r],      __ATOMIC_RELAXED, __HIP_MEMORY_SCOPE_AGENT));
        float hs = __uint_as_float(__hip_atomic_load(&hn_semi[r], __ATOMIC_RELAXED, __HIP_MEMORY_SCOPE_AGENT));
        any |= (hs < h + MARGIN) ? 1 : 0;
    }
    IA[tid] = any;
    __syncthreads();
    for (int s = 256; s; s >>= 1) {
        if (tid < s) IA[tid] |= IA[tid + s];
        __syncthreads();
    }
    const bool has_semi = IA[0] != 0;
    float sum = 0.f; int valid = 0;
    for (int r = tid; r < N; r += 512) {
        float h  = __uint_as_float(__hip_atomic_load(&hp[r], __ATOMIC_RELAXED, __HIP_MEMORY_SCOPE_AGENT));
        float hn = has_semi
            ? __uint_as_float(__hip_atomic_load(&hn_semi[r], __ATOMIC_RELAXED, __HIP_MEMORY_SCOPE_AGENT))
            : __uint_as_float(__hip_atomic_load(&hn_fall[r], __ATOMIC_RELAXED, __HIP_MEMORY_SCOPE_AGENT));
        float t = fmaxf(h - hn + MARGIN, 0.f);
        if (!(t > 0.f)) t = 0.f;        // -inf guard (hn=+inf rows)
        sum += t;
        valid += (t > 0.f) ? 1 : 0;
    }
    FS[tid] = sum; IC[tid] = valid;
    __syncthreads();
    for (int s = 256; s; s >>= 1) {
        if (tid < s) { FS[tid] += FS[tid + s]; IC[tid] += IC[tid + s]; }
        __syncthreads();
    }
    if (tid == 0) {
        float total = FS[0]; int v = IC[0];
        out[0] = (v > 0) ? (total / (float)v) : (total / (float)N);
    }
}

extern "C" void kernel_launch(void* const* d_in, const int* in_sizes, int n_in,
                              void* d_out, int out_size, void* d_ws, size_t ws_size,
                              hipStream_t stream) {
    const float* e      = (const float*)d_in[0];
    const int*   labels = (const int*)d_in[1];
    const int N = in_sizes[1];
    const int D = in_sizes[0] / N;
    float* out = (float*)d_out;

    float*        sq      = (float*)d_ws;
    unsigned int* hp      = (unsigned int*)d_ws + N;
    unsigned int* hn_fall = hp + N;
    unsigned int* hn_semi = hn_fall + N;
    unsigned int* bars    = hn_semi + N;     // 32 counters (128B-spaced) + done @992

    const size_t small_bytes = ((size_t)(4 * N + 1024) * 4 + 255) & ~(size_t)255;
    _Float16* pan = (_Float16*)((char*)d_ws + small_bytes);

    prep_kernel<<<N / 32, 256, 0, stream>>>(e, pan, sq, hp, hn_fall, hn_semi, bars, N, D);

    const int ntx = N / 128, nty = N / 256;  // 32 x 16 tiles = 512 blocks = 2/CU
    fused_kernel<<<ntx * nty, 512, 0, stream>>>(pan, labels, sq, hp, hn_fall, hn_semi,
                                                bars, out, N, D,
                                                (unsigned)ntx, (unsigned)(ntx * nty));
}